// Round 4
// baseline (136.631 us; speedup 1.0000x reference)
//
#include <hip/hip_runtime.h>
#include <hip/hip_fp16.h>

#define NP      4096
#define WINDOW  327
#define HALF    163
#define RL      20
#define NA      262144
#define GN_EPS  1e-6f
#define R       8          // rows (bins) per block
#define NBLK    (NP / R)   // 512 blocks

// fast tanh: 1 - 2/(e^{2x}+1), ~1e-7 abs err
__device__ __forceinline__ float tanh_fast(float x) {
  float e = __expf(2.0f * x);
  return 1.0f - 2.0f / (e + 1.0f);
}

// full 64-lane butterfly sum (masks 1..32)
__device__ __forceinline__ void wave_sum64_2(float& a, float& b) {
#pragma unroll
  for (int m = 1; m < 64; m <<= 1) {
    a += __shfl_xor(a, m, 64);
    b += __shfl_xor(b, m, 64);
  }
}

// LDS float-array layout
#define L_ESP   0               // espan[336] (need 334)
#define L_OBS   336             // obsT[40][8]
#define L_HBUF  656             // hbuf[8][260]
#define L_HCL   2736            // hcL[8][36]
#define L_TOTF  3024            // 12.1 KB floats; + part: 8192 half2 = 32 KB

__global__ __launch_bounds__(512, 4) void dc_table(
    const float* __restrict__ zc,  const float* __restrict__ zt,
    const float* __restrict__ bW0, const float* __restrict__ bb0,
    const float* __restrict__ bs0, const float* __restrict__ bB0,
    const float* __restrict__ bW1, const float* __restrict__ bb1,
    const float* __restrict__ bs1, const float* __restrict__ bB1,
    const float* __restrict__ tW0, const float* __restrict__ tb0,
    const float* __restrict__ tW1, const float* __restrict__ tb1,
    const float* __restrict__ cW,  const float* __restrict__ cb,
    const float* __restrict__ uW,  const float* __restrict__ ub,
    const float* __restrict__ vW,  const float* __restrict__ vb,
    float* __restrict__ tbl)
{
  __shared__ __align__(16) float  smf[L_TOTF];
  __shared__ __align__(16) __half2 part[8 * 8 * 128];   // [wave][row][pair] 32 KB
  float* espan = smf + L_ESP;
  float* obsT  = smf + L_OBS;    // [k][r], stride 8
  float* hbuf  = smf + L_HBUF;   // [r][f], stride 260
  float* hcL   = smf + L_HCL;    // [r][c], stride 36

  const int tid = threadIdx.x;
  const int w   = tid >> 6;      // wave 0..7
  const int l   = tid & 63;      // lane
  const int s0  = blockIdx.x * R;

  // ---- Phase A: shared error span (edge-clamped == jnp.pad 'edge') ----
  for (int t = tid; t < WINDOW + R - 1; t += 512) {
    int c = s0 - HALF + t;
    c = c < 0 ? 0 : (c > NP - 1 ? NP - 1 : c);
    espan[t] = zc[c] - zt[c];
  }
  __syncthreads();

  // ---- Phase B: bilinear-antialias resize of err & gradient -> obsT[40][8] ----
  {
    const float INV  = (float)WINDOW / (float)RL;   // 16.35
    const float RINV = (float)RL / (float)WINDOW;
    for (int task = tid; task < R * 2 * RL; task += 512) {
      int q = task % (2 * RL);
      int r = task / (2 * RL);
      int qq = (q < RL) ? q : q - RL;
      float xs = ((float)qq + 0.5f) * INV - 0.5f;
      int jlo = (int)ceilf(xs - INV);  if (jlo < 0) jlo = 0;
      int jhi = (int)floorf(xs + INV); if (jhi > WINDOW - 1) jhi = WINDOW - 1;
      const float* p = espan + r;
      float wsum = 0.0f, acc = 0.0f;
      for (int j = jlo; j <= jhi; ++j) {
        float wq = 1.0f - fabsf(xs - (float)j) * RINV;
        float v;
        if (q < RL) {
          v = p[j];
        } else {  // jnp.gradient on the window
          v = (j == 0) ? (p[1] - p[0]) :
              (j == WINDOW - 1) ? (p[WINDOW - 1] - p[WINDOW - 2]) :
              0.5f * (p[j + 1] - p[j - 1]);
        }
        wsum += wq;
        acc  += wq * v;
      }
      obsT[q * 8 + r] = acc / wsum;
    }
  }
  __syncthreads();

  float acc[R][4];

  // ---- Layer 0 (40 -> 256), k-split 8-way: wave w owns k in [5w, 5w+5) ----
#pragma unroll
  for (int r = 0; r < R; ++r) { acc[r][0]=0.f; acc[r][1]=0.f; acc[r][2]=0.f; acc[r][3]=0.f; }
  for (int kk = 0; kk < 5; ++kk) {
    int k = w * 5 + kk;
    float4 wt = *(const float4*)&bW0[k * 256 + 4 * l];
    float4 o0 = *(const float4*)&obsT[k * 8];
    float4 o1 = *(const float4*)&obsT[k * 8 + 4];
    const float wv[4] = {wt.x, wt.y, wt.z, wt.w};
    const float ov[8] = {o0.x, o0.y, o0.z, o0.w, o1.x, o1.y, o1.z, o1.w};
#pragma unroll
    for (int r = 0; r < R; ++r)
#pragma unroll
      for (int j = 0; j < 4; ++j) acc[r][j] = fmaf(ov[r], wv[j], acc[r][j]);
  }
#pragma unroll
  for (int r = 0; r < R; ++r) {
    part[w * 1024 + r * 128 + 2 * l]     = __float22half2_rn(make_float2(acc[r][0], acc[r][1]));
    part[w * 1024 + r * 128 + 2 * l + 1] = __float22half2_rn(make_float2(acc[r][2], acc[r][3]));
  }
  __syncthreads();

  // ---- GN0 + tanh: wave rr owns row rr; lane g owns features 4g..4g+3 ----
  {
    const int rr = w, g = l;
    float4 b = *(const float4*)&bb0[4 * g];
    float v0 = b.x, v1 = b.y, v2 = b.z, v3 = b.w;
#pragma unroll
    for (int w2 = 0; w2 < 8; ++w2) {
      float2 p0 = __half22float2(part[w2 * 1024 + rr * 128 + 2 * g]);
      float2 p1 = __half22float2(part[w2 * 1024 + rr * 128 + 2 * g + 1]);
      v0 += p0.x; v1 += p0.y; v2 += p1.x; v3 += p1.y;
    }
    float s = v0 + v1 + v2 + v3;
    float q = v0*v0 + v1*v1 + v2*v2 + v3*v3;
    wave_sum64_2(s, q);
    float mu  = s * (1.0f / 256.0f);
    float var = fmaxf(q * (1.0f / 256.0f) - mu * mu, 0.0f);
    float rv  = rsqrtf(var + GN_EPS);
    float4 sc = *(const float4*)&bs0[4 * g];
    float4 sh = *(const float4*)&bB0[4 * g];
    float4 h;
    h.x = tanh_fast((v0 - mu) * rv * sc.x + sh.x);
    h.y = tanh_fast((v1 - mu) * rv * sc.y + sh.y);
    h.z = tanh_fast((v2 - mu) * rv * sc.z + sh.z);
    h.w = tanh_fast((v3 - mu) * rv * sc.w + sh.w);
    *(float4*)&hbuf[rr * 260 + 4 * g] = h;
  }
  __syncthreads();

  // ---- Layer 1 (256 -> 256), k-split 8-way: wave w owns k in [32w, 32w+32) ----
#pragma unroll
  for (int r = 0; r < R; ++r) { acc[r][0]=0.f; acc[r][1]=0.f; acc[r][2]=0.f; acc[r][3]=0.f; }
  for (int kk = 0; kk < 32; kk += 4) {
    int k0 = w * 32 + kk;
    float4 wt0 = *(const float4*)&bW1[(k0    ) * 256 + 4 * l];
    float4 wt1 = *(const float4*)&bW1[(k0 + 1) * 256 + 4 * l];
    float4 wt2 = *(const float4*)&bW1[(k0 + 2) * 256 + 4 * l];
    float4 wt3 = *(const float4*)&bW1[(k0 + 3) * 256 + 4 * l];
#pragma unroll
    for (int r = 0; r < R; ++r) {
      float4 hv = *(const float4*)&hbuf[r * 260 + k0];   // broadcast
      acc[r][0] = fmaf(hv.x, wt0.x, acc[r][0]); acc[r][1] = fmaf(hv.x, wt0.y, acc[r][1]);
      acc[r][2] = fmaf(hv.x, wt0.z, acc[r][2]); acc[r][3] = fmaf(hv.x, wt0.w, acc[r][3]);
      acc[r][0] = fmaf(hv.y, wt1.x, acc[r][0]); acc[r][1] = fmaf(hv.y, wt1.y, acc[r][1]);
      acc[r][2] = fmaf(hv.y, wt1.z, acc[r][2]); acc[r][3] = fmaf(hv.y, wt1.w, acc[r][3]);
      acc[r][0] = fmaf(hv.z, wt2.x, acc[r][0]); acc[r][1] = fmaf(hv.z, wt2.y, acc[r][1]);
      acc[r][2] = fmaf(hv.z, wt2.z, acc[r][2]); acc[r][3] = fmaf(hv.z, wt2.w, acc[r][3]);
      acc[r][0] = fmaf(hv.w, wt3.x, acc[r][0]); acc[r][1] = fmaf(hv.w, wt3.y, acc[r][1]);
      acc[r][2] = fmaf(hv.w, wt3.z, acc[r][2]); acc[r][3] = fmaf(hv.w, wt3.w, acc[r][3]);
    }
  }
  __syncthreads();   // all hbuf (h0) reads complete before GN1 overwrites
#pragma unroll
  for (int r = 0; r < R; ++r) {
    part[w * 1024 + r * 128 + 2 * l]     = __float22half2_rn(make_float2(acc[r][0], acc[r][1]));
    part[w * 1024 + r * 128 + 2 * l + 1] = __float22half2_rn(make_float2(acc[r][2], acc[r][3]));
  }
  __syncthreads();

  // ---- GN1 + tanh -> hbuf ----
  {
    const int rr = w, g = l;
    float4 b = *(const float4*)&bb1[4 * g];
    float v0 = b.x, v1 = b.y, v2 = b.z, v3 = b.w;
#pragma unroll
    for (int w2 = 0; w2 < 8; ++w2) {
      float2 p0 = __half22float2(part[w2 * 1024 + rr * 128 + 2 * g]);
      float2 p1 = __half22float2(part[w2 * 1024 + rr * 128 + 2 * g + 1]);
      v0 += p0.x; v1 += p0.y; v2 += p1.x; v3 += p1.y;
    }
    float s = v0 + v1 + v2 + v3;
    float q = v0*v0 + v1*v1 + v2*v2 + v3*v3;
    wave_sum64_2(s, q);
    float mu  = s * (1.0f / 256.0f);
    float var = fmaxf(q * (1.0f / 256.0f) - mu * mu, 0.0f);
    float rv  = rsqrtf(var + GN_EPS);
    float4 sc = *(const float4*)&bs1[4 * g];
    float4 sh = *(const float4*)&bB1[4 * g];
    float4 h;
    h.x = tanh_fast((v0 - mu) * rv * sc.x + sh.x);
    h.y = tanh_fast((v1 - mu) * rv * sc.y + sh.y);
    h.z = tanh_fast((v2 - mu) * rv * sc.z + sh.z);
    h.w = tanh_fast((v3 - mu) * rv * sc.w + sh.w);
    *(float4*)&hbuf[rr * 260 + 4 * g] = h;
  }
  __syncthreads();

  // ---- Phase G: hcL[r][c] = cb[c] + h1[r,:].cW[:,c]; K pair-split + shfl combine ----
  {
    int r = tid >> 6;            // wave = row
    int c = l >> 1, kh = l & 1;  // 32 cols x 2 k-halves
    float ga = (kh == 0) ? cb[c] : 0.0f;
    int kbase = kh * 128;
#pragma unroll 4
    for (int k = 0; k < 128; k += 4) {
      float4 hv = *(const float4*)&hbuf[r * 260 + kbase + k];
      ga = fmaf(hv.x, cW[(kbase + k    ) * 32 + c], ga);
      ga = fmaf(hv.y, cW[(kbase + k + 1) * 32 + c], ga);
      ga = fmaf(hv.z, cW[(kbase + k + 2) * 32 + c], ga);
      ga = fmaf(hv.w, cW[(kbase + k + 3) * 32 + c], ga);
    }
    ga += __shfl_xor(ga, 1, 64);
    if (kh == 0) hcL[r * 36 + c] = ga;
  }
  __syncthreads();

  // ---- Tail: 16 endpoint evals (8 bins x {left,right}), 8 threads each ----
  if (tid < 128) {
    int v = tid >> 3, sub = tid & 7;
    int r = v >> 1, e = v & 1;
    int jg = s0 + r + e;
    float xe = (float)jg * (1.0f / 4095.0f);
    float enc[8];
#pragma unroll
    for (int k = 0; k < 4; ++k) {
      float fr = (float)(1 << k);
      float a = (xe * fr) * 3.14159265358979f;
      enc[k]     = sinf(a);
      enc[k + 4] = cosf(a);
    }
    int base = (tid & 63) & ~7;

    float t0v[4];
#pragma unroll
    for (int i = 0; i < 4; ++i) {
      int f = 4 * sub + i;
      float a = tb0[f];
#pragma unroll
      for (int k = 0; k < 8; ++k) a = fmaf(enc[k], tW0[k * 32 + f], a);
      t0v[i] = tanh_fast(a);
    }

    float t1v[4];
#pragma unroll
    for (int i = 0; i < 4; ++i) t1v[i] = tb1[4 * sub + i];
#pragma unroll
    for (int j8 = 0; j8 < 8; ++j8) {
#pragma unroll
      for (int i2 = 0; i2 < 4; ++i2) {
        float tv = __shfl(t0v[i2], base + j8, 64);
        int k = 4 * j8 + i2;
#pragma unroll
        for (int i = 0; i < 4; ++i) t1v[i] = fmaf(tv, tW1[k * 32 + 4 * sub + i], t1v[i]);
      }
    }
#pragma unroll
    for (int i = 0; i < 4; ++i) t1v[i] = tanh_fast(t1v[i]);

    float xvv[4];
#pragma unroll
    for (int i = 0; i < 4; ++i) xvv[i] = hcL[r * 36 + 4 * sub + i];
#pragma unroll
    for (int j8 = 0; j8 < 8; ++j8) {
#pragma unroll
      for (int i2 = 0; i2 < 4; ++i2) {
        float tv = __shfl(t1v[i2], base + j8, 64);
        int k = 4 * j8 + i2;
#pragma unroll
        for (int i = 0; i < 4; ++i) xvv[i] = fmaf(tv, cW[(256 + k) * 32 + 4 * sub + i], xvv[i]);
      }
    }
#pragma unroll
    for (int i = 0; i < 4; ++i) xvv[i] = tanh_fast(xvv[i]);

    float up = 0.f, vp = 0.f;
#pragma unroll
    for (int i = 0; i < 4; ++i) {
      up = fmaf(xvv[i], uW[4 * sub + i], up);
      vp = fmaf(xvv[i], vW[4 * sub + i], vp);
    }
#pragma unroll
    for (int m = 1; m < 8; m <<= 1) {
      up += __shfl_xor(up, m, 64);
      vp += __shfl_xor(vp, m, 64);
    }
    if (sub == 0) {
      int s = s0 + r;
      tbl[4 * s + e]     = 40.0f * tanh_fast(up + ub[0]);
      tbl[4 * s + 2 + e] = tanh_fast(vp + vb[0]);
    }
  }
}

// ---------------- Kernel 2: agents = bin + lerp ----------------
__global__ __launch_bounds__(256) void dc_agents(
    const float* __restrict__ xi_curr, const float4* __restrict__ tbl,
    float* __restrict__ out)
{
  int a = blockIdx.x * 256 + threadIdx.x;
  float xi = xi_curr[a];
  float p = xi * 4095.0f;           // same fp32 product the reference truncates
  int s = (int)p;
  s = s > 4095 ? 4095 : s;
  float t = p - (float)s;           // exact (Sterbenz)
  float4 tb = tbl[s];               // {u_l, u_r, v_l, v_r}
  out[a]      = fmaf(t, tb.y - tb.x, tb.x);
  out[NA + a] = fmaf(t, tb.w - tb.z, tb.z);
}

extern "C" void kernel_launch(void* const* d_in, const int* in_sizes, int n_in,
                              void* d_out, int out_size, void* d_ws, size_t ws_size,
                              hipStream_t stream) {
  const float* zc  = (const float*)d_in[0];
  const float* zt  = (const float*)d_in[1];
  const float* xi  = (const float*)d_in[2];
  const float* bW0 = (const float*)d_in[3];
  const float* bb0 = (const float*)d_in[4];
  const float* bs0 = (const float*)d_in[5];
  const float* bB0 = (const float*)d_in[6];
  const float* bW1 = (const float*)d_in[7];
  const float* bb1 = (const float*)d_in[8];
  const float* bs1 = (const float*)d_in[9];
  const float* bB1 = (const float*)d_in[10];
  const float* tW0 = (const float*)d_in[11];
  const float* tb0 = (const float*)d_in[12];
  const float* tW1 = (const float*)d_in[13];
  const float* tb1 = (const float*)d_in[14];
  const float* cW  = (const float*)d_in[15];
  const float* cb  = (const float*)d_in[16];
  const float* uW  = (const float*)d_in[17];
  const float* ub  = (const float*)d_in[18];
  const float* vW  = (const float*)d_in[19];
  const float* vb  = (const float*)d_in[20];

  float* tbl = (float*)d_ws;        // 4096 x float4 = 64 KB
  float* out = (float*)d_out;

  dc_table<<<NBLK, 512, 0, stream>>>(zc, zt, bW0, bb0, bs0, bB0,
                                     bW1, bb1, bs1, bB1,
                                     tW0, tb0, tW1, tb1, cW, cb,
                                     uW, ub, vW, vb, tbl);
  dc_agents<<<NA / 256, 256, 0, stream>>>(xi, (const float4*)tbl, out);
}

// Round 5
// 133.735 us; speedup vs baseline: 1.0217x; 1.0217x over previous
//
#include <hip/hip_runtime.h>

#define NP      4096
#define WINDOW  327
#define HALF    163
#define RL      20
#define NA      262144
#define GN_EPS  1e-6f
#define R       4          // rows (bins) per block
#define NBLK    (NP / R)   // 1024 blocks

// fast tanh: 1 - 2/(e^{2x}+1), ~1e-7 abs err
__device__ __forceinline__ float tanh_fast(float x) {
  float e = __expf(2.0f * x);
  return 1.0f - 2.0f / (e + 1.0f);
}

// full 64-lane butterfly sum of two values
__device__ __forceinline__ void wave_sum64_2(float& a, float& b) {
#pragma unroll
  for (int m = 1; m < 64; m <<= 1) {
    a += __shfl_xor(a, m, 64);
    b += __shfl_xor(b, m, 64);
  }
}

// LDS float layout
#define L_ESP   0                 // espan[336] (need 330)
#define L_OBS   336               // obsT[40][4]
#define L_HBUF  496               // hbuf[4][260]
#define L_PART  1536              // part[4][4][256] = 4096
#define L_HCL   5632              // hcL[4][36]
#define L_TOT   5776              // 23.1 KB

__global__ __launch_bounds__(256, 4) void dc_table(
    const float* __restrict__ zc,  const float* __restrict__ zt,
    const float* __restrict__ bW0, const float* __restrict__ bb0,
    const float* __restrict__ bs0, const float* __restrict__ bB0,
    const float* __restrict__ bW1, const float* __restrict__ bb1,
    const float* __restrict__ bs1, const float* __restrict__ bB1,
    const float* __restrict__ tW0, const float* __restrict__ tb0,
    const float* __restrict__ tW1, const float* __restrict__ tb1,
    const float* __restrict__ cW,  const float* __restrict__ cb,
    const float* __restrict__ uW,  const float* __restrict__ ub,
    const float* __restrict__ vW,  const float* __restrict__ vb,
    float* __restrict__ tbl)
{
  __shared__ __align__(16) float sm[L_TOT];
  float* espan = sm + L_ESP;
  float* obsT  = sm + L_OBS;     // [k][r], stride 4
  float* hbuf  = sm + L_HBUF;    // [r][f], stride 260
  float* part  = sm + L_PART;    // [w][r][f]
  float* hcL   = sm + L_HCL;     // [r][c], stride 36

  const int tid = threadIdx.x;
  const int w   = tid >> 6;      // wave 0..3
  const int l   = tid & 63;      // lane
  const int s0  = blockIdx.x * R;

  // ---- Phase A: shared error span (edge-clamped == jnp.pad 'edge') ----
  for (int t = tid; t < WINDOW + R - 1; t += 256) {
    int c = s0 - HALF + t;
    c = c < 0 ? 0 : (c > NP - 1 ? NP - 1 : c);
    espan[t] = zc[c] - zt[c];
  }
  __syncthreads();

  // ---- Phase B: bilinear-antialias resize of err & gradient -> obsT[40][4] ----
  {
    const float INV  = (float)WINDOW / (float)RL;   // 16.35
    const float RINV = (float)RL / (float)WINDOW;
    for (int task = tid; task < R * 2 * RL; task += 256) {   // 160 tasks
      int q = task % (2 * RL);
      int r = task / (2 * RL);
      int qq = (q < RL) ? q : q - RL;
      float xs = ((float)qq + 0.5f) * INV - 0.5f;
      int jlo = (int)ceilf(xs - INV);  if (jlo < 0) jlo = 0;
      int jhi = (int)floorf(xs + INV); if (jhi > WINDOW - 1) jhi = WINDOW - 1;
      const float* p = espan + r;
      float wsum = 0.0f, acc = 0.0f;
      for (int j = jlo; j <= jhi; ++j) {
        float wq = 1.0f - fabsf(xs - (float)j) * RINV;
        float v;
        if (q < RL) {
          v = p[j];
        } else {  // jnp.gradient on the window
          v = (j == 0) ? (p[1] - p[0]) :
              (j == WINDOW - 1) ? (p[WINDOW - 1] - p[WINDOW - 2]) :
              0.5f * (p[j + 1] - p[j - 1]);
        }
        wsum += wq;
        acc  += wq * v;
      }
      obsT[q * 4 + r] = acc / wsum;
    }
  }
  __syncthreads();

  float acc[R][4];

  // ---- Layer 0 (40 -> 256), k-split 4-way: wave w owns k in [10w, 10w+10) ----
#pragma unroll
  for (int r = 0; r < R; ++r) { acc[r][0]=0.f; acc[r][1]=0.f; acc[r][2]=0.f; acc[r][3]=0.f; }
#pragma unroll 2
  for (int kk = 0; kk < 10; ++kk) {
    int k = w * 10 + kk;
    float4 wt = *(const float4*)&bW0[k * 256 + 4 * l];
    float4 ov = *(const float4*)&obsT[k * 4];         // rows 0..3 broadcast
    const float wv[4] = {wt.x, wt.y, wt.z, wt.w};
    const float os[4] = {ov.x, ov.y, ov.z, ov.w};
#pragma unroll
    for (int r = 0; r < R; ++r)
#pragma unroll
      for (int j = 0; j < 4; ++j) acc[r][j] = fmaf(os[r], wv[j], acc[r][j]);
  }
#pragma unroll
  for (int r = 0; r < R; ++r)
    *(float4*)&part[w * 1024 + r * 256 + 4 * l] = make_float4(acc[r][0], acc[r][1], acc[r][2], acc[r][3]);
  __syncthreads();

  // ---- GN0 + tanh: wave rr owns row rr; lane g owns features 4g..4g+3 ----
  {
    const int rr = w, g = l;
    float4 b = *(const float4*)&bb0[4 * g];
    float v0 = b.x, v1 = b.y, v2 = b.z, v3 = b.w;
#pragma unroll
    for (int w2 = 0; w2 < 4; ++w2) {
      float4 p4 = *(const float4*)&part[w2 * 1024 + rr * 256 + 4 * g];
      v0 += p4.x; v1 += p4.y; v2 += p4.z; v3 += p4.w;
    }
    float s = v0 + v1 + v2 + v3;
    float q = v0*v0 + v1*v1 + v2*v2 + v3*v3;
    wave_sum64_2(s, q);
    float mu  = s * (1.0f / 256.0f);
    float var = fmaxf(q * (1.0f / 256.0f) - mu * mu, 0.0f);
    float rv  = rsqrtf(var + GN_EPS);
    float4 sc = *(const float4*)&bs0[4 * g];
    float4 sh = *(const float4*)&bB0[4 * g];
    float4 h;
    h.x = tanh_fast((v0 - mu) * rv * sc.x + sh.x);
    h.y = tanh_fast((v1 - mu) * rv * sc.y + sh.y);
    h.z = tanh_fast((v2 - mu) * rv * sc.z + sh.z);
    h.w = tanh_fast((v3 - mu) * rv * sc.w + sh.w);
    *(float4*)&hbuf[rr * 260 + 4 * g] = h;
  }
  __syncthreads();

  // ---- Layer 1 (256 -> 256), k-split 4-way: wave w owns k in [64w, 64w+64) ----
#pragma unroll
  for (int r = 0; r < R; ++r) { acc[r][0]=0.f; acc[r][1]=0.f; acc[r][2]=0.f; acc[r][3]=0.f; }
#pragma unroll 2
  for (int kk = 0; kk < 64; kk += 4) {
    int k0 = w * 64 + kk;
    float4 wt0 = *(const float4*)&bW1[(k0    ) * 256 + 4 * l];
    float4 wt1 = *(const float4*)&bW1[(k0 + 1) * 256 + 4 * l];
    float4 wt2 = *(const float4*)&bW1[(k0 + 2) * 256 + 4 * l];
    float4 wt3 = *(const float4*)&bW1[(k0 + 3) * 256 + 4 * l];
#pragma unroll
    for (int r = 0; r < R; ++r) {
      float4 hv = *(const float4*)&hbuf[r * 260 + k0];   // broadcast
      acc[r][0] = fmaf(hv.x, wt0.x, acc[r][0]); acc[r][1] = fmaf(hv.x, wt0.y, acc[r][1]);
      acc[r][2] = fmaf(hv.x, wt0.z, acc[r][2]); acc[r][3] = fmaf(hv.x, wt0.w, acc[r][3]);
      acc[r][0] = fmaf(hv.y, wt1.x, acc[r][0]); acc[r][1] = fmaf(hv.y, wt1.y, acc[r][1]);
      acc[r][2] = fmaf(hv.y, wt1.z, acc[r][2]); acc[r][3] = fmaf(hv.y, wt1.w, acc[r][3]);
      acc[r][0] = fmaf(hv.z, wt2.x, acc[r][0]); acc[r][1] = fmaf(hv.z, wt2.y, acc[r][1]);
      acc[r][2] = fmaf(hv.z, wt2.z, acc[r][2]); acc[r][3] = fmaf(hv.z, wt2.w, acc[r][3]);
      acc[r][0] = fmaf(hv.w, wt3.x, acc[r][0]); acc[r][1] = fmaf(hv.w, wt3.y, acc[r][1]);
      acc[r][2] = fmaf(hv.w, wt3.z, acc[r][2]); acc[r][3] = fmaf(hv.w, wt3.w, acc[r][3]);
    }
  }
#pragma unroll
  for (int r = 0; r < R; ++r)
    *(float4*)&part[w * 1024 + r * 256 + 4 * l] = make_float4(acc[r][0], acc[r][1], acc[r][2], acc[r][3]);
  __syncthreads();   // orders all hbuf(h0) reads before GN1's hbuf writes

  // ---- GN1 + tanh -> hbuf ----
  {
    const int rr = w, g = l;
    float4 b = *(const float4*)&bb1[4 * g];
    float v0 = b.x, v1 = b.y, v2 = b.z, v3 = b.w;
#pragma unroll
    for (int w2 = 0; w2 < 4; ++w2) {
      float4 p4 = *(const float4*)&part[w2 * 1024 + rr * 256 + 4 * g];
      v0 += p4.x; v1 += p4.y; v2 += p4.z; v3 += p4.w;
    }
    float s = v0 + v1 + v2 + v3;
    float q = v0*v0 + v1*v1 + v2*v2 + v3*v3;
    wave_sum64_2(s, q);
    float mu  = s * (1.0f / 256.0f);
    float var = fmaxf(q * (1.0f / 256.0f) - mu * mu, 0.0f);
    float rv  = rsqrtf(var + GN_EPS);
    float4 sc = *(const float4*)&bs1[4 * g];
    float4 sh = *(const float4*)&bB1[4 * g];
    float4 h;
    h.x = tanh_fast((v0 - mu) * rv * sc.x + sh.x);
    h.y = tanh_fast((v1 - mu) * rv * sc.y + sh.y);
    h.z = tanh_fast((v2 - mu) * rv * sc.z + sh.z);
    h.w = tanh_fast((v3 - mu) * rv * sc.w + sh.w);
    *(float4*)&hbuf[rr * 260 + 4 * g] = h;
  }
  __syncthreads();

  // ---- Phase G: hcL[r][c] = cb[c] + h1[r,:].cW[:,c]; K pair-split + shfl combine ----
  {
    int r = tid >> 6;            // wave = row
    int c = l >> 1, kh = l & 1;  // 32 cols x 2 k-halves
    float ga = (kh == 0) ? cb[c] : 0.0f;
    int kbase = kh * 128;
#pragma unroll 4
    for (int k = 0; k < 128; k += 4) {
      float4 hv = *(const float4*)&hbuf[r * 260 + kbase + k];
      ga = fmaf(hv.x, cW[(kbase + k    ) * 32 + c], ga);
      ga = fmaf(hv.y, cW[(kbase + k + 1) * 32 + c], ga);
      ga = fmaf(hv.z, cW[(kbase + k + 2) * 32 + c], ga);
      ga = fmaf(hv.w, cW[(kbase + k + 3) * 32 + c], ga);
    }
    ga += __shfl_xor(ga, 1, 64);
    if (kh == 0) hcL[r * 36 + c] = ga;
  }
  __syncthreads();

  // ---- Tail: 8 endpoint evals (4 bins x {left,right}), 8 threads each (wave 0) ----
  if (tid < 64) {
    int v = tid >> 3, sub = tid & 7;
    int r = v >> 1, e = v & 1;
    int jg = s0 + r + e;
    float xe = (float)jg * (1.0f / 4095.0f);
    float enc[8];
#pragma unroll
    for (int k = 0; k < 4; ++k) {
      float fr = (float)(1 << k);
      float a = (xe * fr) * 3.14159265358979f;
      enc[k]     = sinf(a);
      enc[k + 4] = cosf(a);
    }
    int base = tid & ~7;

    float t0v[4];
#pragma unroll
    for (int i = 0; i < 4; ++i) {
      int f = 4 * sub + i;
      float a = tb0[f];
#pragma unroll
      for (int k = 0; k < 8; ++k) a = fmaf(enc[k], tW0[k * 32 + f], a);
      t0v[i] = tanh_fast(a);
    }

    float t1v[4];
#pragma unroll
    for (int i = 0; i < 4; ++i) t1v[i] = tb1[4 * sub + i];
#pragma unroll
    for (int j8 = 0; j8 < 8; ++j8) {
#pragma unroll
      for (int i2 = 0; i2 < 4; ++i2) {
        float tv = __shfl(t0v[i2], base + j8, 64);
        int k = 4 * j8 + i2;
#pragma unroll
        for (int i = 0; i < 4; ++i) t1v[i] = fmaf(tv, tW1[k * 32 + 4 * sub + i], t1v[i]);
      }
    }
#pragma unroll
    for (int i = 0; i < 4; ++i) t1v[i] = tanh_fast(t1v[i]);

    float xvv[4];
#pragma unroll
    for (int i = 0; i < 4; ++i) xvv[i] = hcL[r * 36 + 4 * sub + i];
#pragma unroll
    for (int j8 = 0; j8 < 8; ++j8) {
#pragma unroll
      for (int i2 = 0; i2 < 4; ++i2) {
        float tv = __shfl(t1v[i2], base + j8, 64);
        int k = 4 * j8 + i2;
#pragma unroll
        for (int i = 0; i < 4; ++i) xvv[i] = fmaf(tv, cW[(256 + k) * 32 + 4 * sub + i], xvv[i]);
      }
    }
#pragma unroll
    for (int i = 0; i < 4; ++i) xvv[i] = tanh_fast(xvv[i]);

    float up = 0.f, vp = 0.f;
#pragma unroll
    for (int i = 0; i < 4; ++i) {
      up = fmaf(xvv[i], uW[4 * sub + i], up);
      vp = fmaf(xvv[i], vW[4 * sub + i], vp);
    }
#pragma unroll
    for (int m = 1; m < 8; m <<= 1) {
      up += __shfl_xor(up, m, 64);
      vp += __shfl_xor(vp, m, 64);
    }
    if (sub == 0) {
      int s = s0 + r;
      tbl[4 * s + e]     = 40.0f * tanh_fast(up + ub[0]);
      tbl[4 * s + 2 + e] = tanh_fast(vp + vb[0]);
    }
  }
}

// ---------------- Kernel 2: agents = bin + lerp ----------------
__global__ __launch_bounds__(256) void dc_agents(
    const float* __restrict__ xi_curr, const float4* __restrict__ tbl,
    float* __restrict__ out)
{
  int a = blockIdx.x * 256 + threadIdx.x;
  float xi = xi_curr[a];
  float p = xi * 4095.0f;           // same fp32 product the reference truncates
  int s = (int)p;
  s = s > 4095 ? 4095 : s;
  float t = p - (float)s;           // exact (Sterbenz)
  float4 tb = tbl[s];               // {u_l, u_r, v_l, v_r}
  out[a]      = fmaf(t, tb.y - tb.x, tb.x);
  out[NA + a] = fmaf(t, tb.w - tb.z, tb.z);
}

extern "C" void kernel_launch(void* const* d_in, const int* in_sizes, int n_in,
                              void* d_out, int out_size, void* d_ws, size_t ws_size,
                              hipStream_t stream) {
  const float* zc  = (const float*)d_in[0];
  const float* zt  = (const float*)d_in[1];
  const float* xi  = (const float*)d_in[2];
  const float* bW0 = (const float*)d_in[3];
  const float* bb0 = (const float*)d_in[4];
  const float* bs0 = (const float*)d_in[5];
  const float* bB0 = (const float*)d_in[6];
  const float* bW1 = (const float*)d_in[7];
  const float* bb1 = (const float*)d_in[8];
  const float* bs1 = (const float*)d_in[9];
  const float* bB1 = (const float*)d_in[10];
  const float* tW0 = (const float*)d_in[11];
  const float* tb0 = (const float*)d_in[12];
  const float* tW1 = (const float*)d_in[13];
  const float* tb1 = (const float*)d_in[14];
  const float* cW  = (const float*)d_in[15];
  const float* cb  = (const float*)d_in[16];
  const float* uW  = (const float*)d_in[17];
  const float* ub  = (const float*)d_in[18];
  const float* vW  = (const float*)d_in[19];
  const float* vb  = (const float*)d_in[20];

  float* tbl = (float*)d_ws;        // 4096 x float4 = 64 KB
  float* out = (float*)d_out;

  dc_table<<<NBLK, 256, 0, stream>>>(zc, zt, bW0, bb0, bs0, bB0,
                                     bW1, bb1, bs1, bB1,
                                     tW0, tb0, tW1, tb1, cW, cb,
                                     uW, ub, vW, vb, tbl);
  dc_agents<<<NA / 256, 256, 0, stream>>>(xi, (const float4*)tbl, out);
}

// Round 6
// 129.078 us; speedup vs baseline: 1.0585x; 1.0361x over previous
//
#include <hip/hip_runtime.h>

#define NP      4096
#define WINDOW  327
#define HALF    163
#define RL      20
#define NA      262144
#define GN_EPS  1e-6f
#define R       8          // rows (bins) per block
#define NBLK    (NP / R)   // 512 blocks -> 2 blocks/CU

// fast tanh: 1 - 2/(e^{2x}+1), ~1e-7 abs err
__device__ __forceinline__ float tanh_fast(float x) {
  float e = __expf(2.0f * x);
  return 1.0f - 2.0f / (e + 1.0f);
}

// butterfly sum over 32-lane groups (row groups are 32 consecutive lanes)
__device__ __forceinline__ void halfwave_sum2(float& a, float& b) {
#pragma unroll
  for (int m = 1; m < 32; m <<= 1) {
    a += __shfl_xor(a, m, 64);
    b += __shfl_xor(b, m, 64);
  }
}

// LDS float layout (44.9 KB -> 2 blocks/CU)
#define L_ESP   0               // espan[336] (need 334)
#define L_OBS   336             // obsT[40][8]
#define L_HBUF  656             // hbuf[8][260]
#define L_PART  2736            // part[4][8][256]
#define L_HCL   10928           // hcL[8][36]
#define L_TOT   11216

__global__ __launch_bounds__(256, 2) void dc_table(
    const float* __restrict__ zc,  const float* __restrict__ zt,
    const float* __restrict__ bW0, const float* __restrict__ bb0,
    const float* __restrict__ bs0, const float* __restrict__ bB0,
    const float* __restrict__ bW1, const float* __restrict__ bb1,
    const float* __restrict__ bs1, const float* __restrict__ bB1,
    const float* __restrict__ tW0, const float* __restrict__ tb0,
    const float* __restrict__ tW1, const float* __restrict__ tb1,
    const float* __restrict__ cW,  const float* __restrict__ cb,
    const float* __restrict__ uW,  const float* __restrict__ ub,
    const float* __restrict__ vW,  const float* __restrict__ vb,
    float* __restrict__ tbl)
{
  __shared__ __align__(16) float sm[L_TOT];
  float* espan = sm + L_ESP;
  float* obsT  = sm + L_OBS;     // [k][r], stride 8
  float* hbuf  = sm + L_HBUF;    // [r][f], stride 260
  float* part  = sm + L_PART;    // [w][r][f]
  float* hcL   = sm + L_HCL;     // [r][c], stride 36

  const int tid = threadIdx.x;
  const int w   = tid >> 6;      // wave 0..3
  const int l   = tid & 63;      // lane
  const int rG  = tid >> 5;      // row-group 0..7 (GN + phase G)
  const int cG  = tid & 31;      // col within group
  const int s0  = blockIdx.x * R;

  // ---- Phase A: shared error span (edge-clamped == jnp.pad 'edge') ----
  for (int t = tid; t < WINDOW + R - 1; t += 256) {
    int c = s0 - HALF + t;
    c = c < 0 ? 0 : (c > NP - 1 ? NP - 1 : c);
    espan[t] = zc[c] - zt[c];
  }
  __syncthreads();

  // prefetch layer-0 first weight row (completes during Phase B)
  const float* w0p = bW0 + (w * 10) * 256 + 4 * l;
  float4 wt0_n = *(const float4*)w0p;

  // ---- Phase B: bilinear-antialias resize of err & gradient -> obsT[40][8] ----
  {
    const float INV  = (float)WINDOW / (float)RL;   // 16.35
    const float RINV = (float)RL / (float)WINDOW;
    for (int task = tid; task < R * 2 * RL; task += 256) {   // 320 tasks
      int q = task % (2 * RL);
      int r = task / (2 * RL);
      int qq = (q < RL) ? q : q - RL;
      float xs = ((float)qq + 0.5f) * INV - 0.5f;
      int jlo = (int)ceilf(xs - INV);  if (jlo < 0) jlo = 0;
      int jhi = (int)floorf(xs + INV); if (jhi > WINDOW - 1) jhi = WINDOW - 1;
      const float* p = espan + r;
      float wsum = 0.0f, acc2 = 0.0f;
      for (int j = jlo; j <= jhi; ++j) {
        float wq = 1.0f - fabsf(xs - (float)j) * RINV;
        float v;
        if (q < RL) {
          v = p[j];
        } else {  // jnp.gradient on the window
          v = (j == 0) ? (p[1] - p[0]) :
              (j == WINDOW - 1) ? (p[WINDOW - 1] - p[WINDOW - 2]) :
              0.5f * (p[j + 1] - p[j - 1]);
        }
        wsum += wq;
        acc2 += wq * v;
      }
      obsT[q * 8 + r] = acc2 / wsum;
    }
  }
  __syncthreads();

  float acc[R][4];

  // ---- Layer 0 (40 -> 256), k-split 4-way, 1-deep weight prefetch ----
#pragma unroll
  for (int r = 0; r < R; ++r) { acc[r][0]=0.f; acc[r][1]=0.f; acc[r][2]=0.f; acc[r][3]=0.f; }
#pragma unroll
  for (int kk = 0; kk < 10; ++kk) {
    float4 wt = wt0_n;
    if (kk < 9) wt0_n = *(const float4*)(w0p + (kk + 1) * 256);
    int k = w * 10 + kk;
    float4 o0 = *(const float4*)&obsT[k * 8];
    float4 o1 = *(const float4*)&obsT[k * 8 + 4];
    const float os[8] = {o0.x, o0.y, o0.z, o0.w, o1.x, o1.y, o1.z, o1.w};
    const float wv[4] = {wt.x, wt.y, wt.z, wt.w};
#pragma unroll
    for (int r = 0; r < R; ++r)
#pragma unroll
      for (int j = 0; j < 4; ++j) acc[r][j] = fmaf(os[r], wv[j], acc[r][j]);
  }
#pragma unroll
  for (int r = 0; r < R; ++r)
    *(float4*)&part[w * 2048 + r * 256 + 4 * l] = make_float4(acc[r][0], acc[r][1], acc[r][2], acc[r][3]);
  __syncthreads();

  // ---- GN0 + tanh (and prefetch layer-1 first 4 weight rows during it) ----
  const float* w1p = bW1 + (w * 64) * 256 + 4 * l;
  float4 wt_n0 = *(const float4*)(w1p);
  float4 wt_n1 = *(const float4*)(w1p + 256);
  float4 wt_n2 = *(const float4*)(w1p + 512);
  float4 wt_n3 = *(const float4*)(w1p + 768);
  {
    float val[8];
    {
      float4 b0 = *(const float4*)&bb0[8 * cG];
      float4 b1 = *(const float4*)&bb0[8 * cG + 4];
      val[0]=b0.x; val[1]=b0.y; val[2]=b0.z; val[3]=b0.w;
      val[4]=b1.x; val[5]=b1.y; val[6]=b1.z; val[7]=b1.w;
    }
#pragma unroll
    for (int w2 = 0; w2 < 4; ++w2) {
      float4 p0 = *(const float4*)&part[w2 * 2048 + rG * 256 + 8 * cG];
      float4 p1 = *(const float4*)&part[w2 * 2048 + rG * 256 + 8 * cG + 4];
      val[0]+=p0.x; val[1]+=p0.y; val[2]+=p0.z; val[3]+=p0.w;
      val[4]+=p1.x; val[5]+=p1.y; val[6]+=p1.z; val[7]+=p1.w;
    }
    float s = 0.f, q = 0.f;
#pragma unroll
    for (int i = 0; i < 8; ++i) { s += val[i]; q += val[i] * val[i]; }
    halfwave_sum2(s, q);
    float mu  = s * (1.0f / 256.0f);
    float var = fmaxf(q * (1.0f / 256.0f) - mu * mu, 0.0f);
    float rv  = rsqrtf(var + GN_EPS);
    float4 sc0 = *(const float4*)&bs0[8 * cG];
    float4 sc1 = *(const float4*)&bs0[8 * cG + 4];
    float4 sh0 = *(const float4*)&bB0[8 * cG];
    float4 sh1 = *(const float4*)&bB0[8 * cG + 4];
    const float sc[8] = {sc0.x,sc0.y,sc0.z,sc0.w,sc1.x,sc1.y,sc1.z,sc1.w};
    const float sh[8] = {sh0.x,sh0.y,sh0.z,sh0.w,sh1.x,sh1.y,sh1.z,sh1.w};
    float h[8];
#pragma unroll
    for (int i = 0; i < 8; ++i) h[i] = tanh_fast((val[i] - mu) * rv * sc[i] + sh[i]);
    *(float4*)&hbuf[rG * 260 + 8 * cG]     = make_float4(h[0], h[1], h[2], h[3]);
    *(float4*)&hbuf[rG * 260 + 8 * cG + 4] = make_float4(h[4], h[5], h[6], h[7]);
  }
  __syncthreads();

  // ---- Layer 1 (256 -> 256), k-split 4-way, 4-row weight prefetch ----
#pragma unroll
  for (int r = 0; r < R; ++r) { acc[r][0]=0.f; acc[r][1]=0.f; acc[r][2]=0.f; acc[r][3]=0.f; }
  for (int kk = 0; kk < 64; kk += 4) {
    float4 wt0 = wt_n0, wt1 = wt_n1, wt2 = wt_n2, wt3 = wt_n3;
    if (kk < 60) {
      wt_n0 = *(const float4*)(w1p + (kk + 4) * 256);
      wt_n1 = *(const float4*)(w1p + (kk + 5) * 256);
      wt_n2 = *(const float4*)(w1p + (kk + 6) * 256);
      wt_n3 = *(const float4*)(w1p + (kk + 7) * 256);
    }
    int k0 = w * 64 + kk;
#pragma unroll
    for (int r = 0; r < R; ++r) {
      float4 hv = *(const float4*)&hbuf[r * 260 + k0];   // broadcast
      acc[r][0] = fmaf(hv.x, wt0.x, acc[r][0]); acc[r][1] = fmaf(hv.x, wt0.y, acc[r][1]);
      acc[r][2] = fmaf(hv.x, wt0.z, acc[r][2]); acc[r][3] = fmaf(hv.x, wt0.w, acc[r][3]);
      acc[r][0] = fmaf(hv.y, wt1.x, acc[r][0]); acc[r][1] = fmaf(hv.y, wt1.y, acc[r][1]);
      acc[r][2] = fmaf(hv.y, wt1.z, acc[r][2]); acc[r][3] = fmaf(hv.y, wt1.w, acc[r][3]);
      acc[r][0] = fmaf(hv.z, wt2.x, acc[r][0]); acc[r][1] = fmaf(hv.z, wt2.y, acc[r][1]);
      acc[r][2] = fmaf(hv.z, wt2.z, acc[r][2]); acc[r][3] = fmaf(hv.z, wt2.w, acc[r][3]);
      acc[r][0] = fmaf(hv.w, wt3.x, acc[r][0]); acc[r][1] = fmaf(hv.w, wt3.y, acc[r][1]);
      acc[r][2] = fmaf(hv.w, wt3.z, acc[r][2]); acc[r][3] = fmaf(hv.w, wt3.w, acc[r][3]);
    }
  }
#pragma unroll
  for (int r = 0; r < R; ++r)
    *(float4*)&part[w * 2048 + r * 256 + 4 * l] = make_float4(acc[r][0], acc[r][1], acc[r][2], acc[r][3]);
  __syncthreads();   // orders all hbuf(h0) reads before GN1's hbuf writes

  // ---- GN1 + tanh (and prefetch phase-G first cW chunk during it) ----
  const float* cwp = cW + cG;
  float cwn[8];
#pragma unroll
  for (int i = 0; i < 8; ++i) cwn[i] = cwp[i * 32];
  {
    float val[8];
    {
      float4 b0 = *(const float4*)&bb1[8 * cG];
      float4 b1 = *(const float4*)&bb1[8 * cG + 4];
      val[0]=b0.x; val[1]=b0.y; val[2]=b0.z; val[3]=b0.w;
      val[4]=b1.x; val[5]=b1.y; val[6]=b1.z; val[7]=b1.w;
    }
#pragma unroll
    for (int w2 = 0; w2 < 4; ++w2) {
      float4 p0 = *(const float4*)&part[w2 * 2048 + rG * 256 + 8 * cG];
      float4 p1 = *(const float4*)&part[w2 * 2048 + rG * 256 + 8 * cG + 4];
      val[0]+=p0.x; val[1]+=p0.y; val[2]+=p0.z; val[3]+=p0.w;
      val[4]+=p1.x; val[5]+=p1.y; val[6]+=p1.z; val[7]+=p1.w;
    }
    float s = 0.f, q = 0.f;
#pragma unroll
    for (int i = 0; i < 8; ++i) { s += val[i]; q += val[i] * val[i]; }
    halfwave_sum2(s, q);
    float mu  = s * (1.0f / 256.0f);
    float var = fmaxf(q * (1.0f / 256.0f) - mu * mu, 0.0f);
    float rv  = rsqrtf(var + GN_EPS);
    float4 sc0 = *(const float4*)&bs1[8 * cG];
    float4 sc1 = *(const float4*)&bs1[8 * cG + 4];
    float4 sh0 = *(const float4*)&bB1[8 * cG];
    float4 sh1 = *(const float4*)&bB1[8 * cG + 4];
    const float sc[8] = {sc0.x,sc0.y,sc0.z,sc0.w,sc1.x,sc1.y,sc1.z,sc1.w};
    const float sh[8] = {sh0.x,sh0.y,sh0.z,sh0.w,sh1.x,sh1.y,sh1.z,sh1.w};
    float h[8];
#pragma unroll
    for (int i = 0; i < 8; ++i) h[i] = tanh_fast((val[i] - mu) * rv * sc[i] + sh[i]);
    *(float4*)&hbuf[rG * 260 + 8 * cG]     = make_float4(h[0], h[1], h[2], h[3]);
    *(float4*)&hbuf[rG * 260 + 8 * cG + 4] = make_float4(h[4], h[5], h[6], h[7]);
  }
  __syncthreads();

  // ---- Phase G: hcL[r][c] = cb[c] + h1[r,:].cW[:,c], 8-deep cW prefetch ----
  {
    float ga = 0.0f;
    for (int k = 0; k < 256; k += 8) {
      float cw0=cwn[0], cw1=cwn[1], cw2=cwn[2], cw3=cwn[3];
      float cw4=cwn[4], cw5=cwn[5], cw6=cwn[6], cw7=cwn[7];
      if (k < 248) {
#pragma unroll
        for (int i = 0; i < 8; ++i) cwn[i] = cwp[(k + 8 + i) * 32];
      }
      float4 h0 = *(const float4*)&hbuf[rG * 260 + k];
      float4 h1 = *(const float4*)&hbuf[rG * 260 + k + 4];
      ga = fmaf(h0.x, cw0, ga); ga = fmaf(h0.y, cw1, ga);
      ga = fmaf(h0.z, cw2, ga); ga = fmaf(h0.w, cw3, ga);
      ga = fmaf(h1.x, cw4, ga); ga = fmaf(h1.y, cw5, ga);
      ga = fmaf(h1.z, cw6, ga); ga = fmaf(h1.w, cw7, ga);
    }
    hcL[rG * 36 + cG] = ga + cb[cG];
  }
  __syncthreads();

  // ---- Tail: 16 endpoint evals (8 bins x {left,right}), 8 threads each ----
  if (tid < 128) {
    int v = tid >> 3, sub = tid & 7;
    int r = v >> 1, e = v & 1;
    int jg = s0 + r + e;
    float xe = (float)jg * (1.0f / 4095.0f);
    float enc[8];
#pragma unroll
    for (int k = 0; k < 4; ++k) {
      float fr = (float)(1 << k);
      float a = (xe * fr) * 3.14159265358979f;
      enc[k]     = sinf(a);
      enc[k + 4] = cosf(a);
    }
    int base = (tid & 63) & ~7;

    float t0v[4];
    {
      float4 b = *(const float4*)&tb0[4 * sub];
      t0v[0]=b.x; t0v[1]=b.y; t0v[2]=b.z; t0v[3]=b.w;
    }
#pragma unroll
    for (int k = 0; k < 8; ++k) {
      float4 wq = *(const float4*)&tW0[k * 32 + 4 * sub];
      t0v[0] = fmaf(enc[k], wq.x, t0v[0]);
      t0v[1] = fmaf(enc[k], wq.y, t0v[1]);
      t0v[2] = fmaf(enc[k], wq.z, t0v[2]);
      t0v[3] = fmaf(enc[k], wq.w, t0v[3]);
    }
#pragma unroll
    for (int i = 0; i < 4; ++i) t0v[i] = tanh_fast(t0v[i]);

    float t1v[4];
    {
      float4 b = *(const float4*)&tb1[4 * sub];
      t1v[0]=b.x; t1v[1]=b.y; t1v[2]=b.z; t1v[3]=b.w;
    }
#pragma unroll
    for (int j8 = 0; j8 < 8; ++j8) {
#pragma unroll
      for (int i2 = 0; i2 < 4; ++i2) {
        float tv = __shfl(t0v[i2], base + j8, 64);
        float4 wq = *(const float4*)&tW1[(4 * j8 + i2) * 32 + 4 * sub];
        t1v[0] = fmaf(tv, wq.x, t1v[0]);
        t1v[1] = fmaf(tv, wq.y, t1v[1]);
        t1v[2] = fmaf(tv, wq.z, t1v[2]);
        t1v[3] = fmaf(tv, wq.w, t1v[3]);
      }
    }
#pragma unroll
    for (int i = 0; i < 4; ++i) t1v[i] = tanh_fast(t1v[i]);

    float xvv[4];
    {
      float4 hq = *(const float4*)&hcL[r * 36 + 4 * sub];
      xvv[0]=hq.x; xvv[1]=hq.y; xvv[2]=hq.z; xvv[3]=hq.w;
    }
#pragma unroll
    for (int j8 = 0; j8 < 8; ++j8) {
#pragma unroll
      for (int i2 = 0; i2 < 4; ++i2) {
        float tv = __shfl(t1v[i2], base + j8, 64);
        float4 wq = *(const float4*)&cW[(256 + 4 * j8 + i2) * 32 + 4 * sub];
        xvv[0] = fmaf(tv, wq.x, xvv[0]);
        xvv[1] = fmaf(tv, wq.y, xvv[1]);
        xvv[2] = fmaf(tv, wq.z, xvv[2]);
        xvv[3] = fmaf(tv, wq.w, xvv[3]);
      }
    }
#pragma unroll
    for (int i = 0; i < 4; ++i) xvv[i] = tanh_fast(xvv[i]);

    float4 wu = *(const float4*)&uW[4 * sub];
    float4 wv = *(const float4*)&vW[4 * sub];
    float up = xvv[0]*wu.x + xvv[1]*wu.y + xvv[2]*wu.z + xvv[3]*wu.w;
    float vp = xvv[0]*wv.x + xvv[1]*wv.y + xvv[2]*wv.z + xvv[3]*wv.w;
#pragma unroll
    for (int m = 1; m < 8; m <<= 1) {
      up += __shfl_xor(up, m, 64);
      vp += __shfl_xor(vp, m, 64);
    }
    if (sub == 0) {
      int s = s0 + r;
      tbl[4 * s + e]     = 40.0f * tanh_fast(up + ub[0]);
      tbl[4 * s + 2 + e] = tanh_fast(vp + vb[0]);
    }
  }
}

// ---------------- Kernel 2: agents = bin + lerp ----------------
__global__ __launch_bounds__(256) void dc_agents(
    const float* __restrict__ xi_curr, const float4* __restrict__ tbl,
    float* __restrict__ out)
{
  int a = blockIdx.x * 256 + threadIdx.x;
  float xi = xi_curr[a];
  float p = xi * 4095.0f;           // same fp32 product the reference truncates
  int s = (int)p;
  s = s > 4095 ? 4095 : s;
  float t = p - (float)s;           // exact (Sterbenz)
  float4 tb = tbl[s];               // {u_l, u_r, v_l, v_r}
  out[a]      = fmaf(t, tb.y - tb.x, tb.x);
  out[NA + a] = fmaf(t, tb.w - tb.z, tb.z);
}

extern "C" void kernel_launch(void* const* d_in, const int* in_sizes, int n_in,
                              void* d_out, int out_size, void* d_ws, size_t ws_size,
                              hipStream_t stream) {
  const float* zc  = (const float*)d_in[0];
  const float* zt  = (const float*)d_in[1];
  const float* xi  = (const float*)d_in[2];
  const float* bW0 = (const float*)d_in[3];
  const float* bb0 = (const float*)d_in[4];
  const float* bs0 = (const float*)d_in[5];
  const float* bB0 = (const float*)d_in[6];
  const float* bW1 = (const float*)d_in[7];
  const float* bb1 = (const float*)d_in[8];
  const float* bs1 = (const float*)d_in[9];
  const float* bB1 = (const float*)d_in[10];
  const float* tW0 = (const float*)d_in[11];
  const float* tb0 = (const float*)d_in[12];
  const float* tW1 = (const float*)d_in[13];
  const float* tb1 = (const float*)d_in[14];
  const float* cW  = (const float*)d_in[15];
  const float* cb  = (const float*)d_in[16];
  const float* uW  = (const float*)d_in[17];
  const float* ub  = (const float*)d_in[18];
  const float* vW  = (const float*)d_in[19];
  const float* vb  = (const float*)d_in[20];

  float* tbl = (float*)d_ws;        // 4096 x float4 = 64 KB
  float* out = (float*)d_out;

  dc_table<<<NBLK, 256, 0, stream>>>(zc, zt, bW0, bb0, bs0, bB0,
                                     bW1, bb1, bs1, bB1,
                                     tW0, tb0, tW1, tb1, cW, cb,
                                     uW, ub, vW, vb, tbl);
  dc_agents<<<NA / 256, 256, 0, stream>>>(xi, (const float4*)tbl, out);
}

// Round 7
// 127.921 us; speedup vs baseline: 1.0681x; 1.0090x over previous
//
#include <hip/hip_runtime.h>

#define NP      4096
#define WINDOW  327
#define HALF    163
#define RL      20
#define NA      262144
#define GN_EPS  1e-6f
#define R       8          // rows (bins) per block
#define NBLK    (NP / R)   // 512 blocks -> 2 blocks/CU

// fast tanh: 1 - 2/(e^{2x}+1), ~1e-7 abs err
__device__ __forceinline__ float tanh_fast(float x) {
  float e = __expf(2.0f * x);
  return 1.0f - 2.0f / (e + 1.0f);
}

// butterfly sum over 32-lane groups (row groups are 32 consecutive lanes)
__device__ __forceinline__ void halfwave_sum2(float& a, float& b) {
#pragma unroll
  for (int m = 1; m < 32; m <<= 1) {
    a += __shfl_xor(a, m, 64);
    b += __shfl_xor(b, m, 64);
  }
}

// LDS float layout (78.1 KB -> 2 blocks/CU)
#define L_ESP   0               // espan[336] (need 334)
#define L_OBS   336             // obsT[40][8]
#define L_HBUF  656             // hbuf[8][260]
#define L_PART  2736            // part[4][8][256]  (reused as tail-weight stage)
#define L_HCL   10928           // hcL[8][36]
#define L_CWS   11216           // cWs[32][260] transposed cW-top
#define L_TOT   19536

// tail-stage offsets relative to sm + L_PART
#define TS_TW0  0      // [8][32]
#define TS_TB0  256    // [32]
#define TS_TW1  288    // [32][32]
#define TS_TB1  1312   // [32]
#define TS_CWB  1344   // cW rows 256..287 [32][32]
#define TS_UW   2368   // [32]
#define TS_VW   2400   // [32]
#define TS_UB   2432
#define TS_VB   2433

__global__ __launch_bounds__(256, 2) void dc_table(
    const float* __restrict__ zc,  const float* __restrict__ zt,
    const float* __restrict__ bW0, const float* __restrict__ bb0,
    const float* __restrict__ bs0, const float* __restrict__ bB0,
    const float* __restrict__ bW1, const float* __restrict__ bb1,
    const float* __restrict__ bs1, const float* __restrict__ bB1,
    const float* __restrict__ tW0, const float* __restrict__ tb0,
    const float* __restrict__ tW1, const float* __restrict__ tb1,
    const float* __restrict__ cW,  const float* __restrict__ cb,
    const float* __restrict__ uW,  const float* __restrict__ ub,
    const float* __restrict__ vW,  const float* __restrict__ vb,
    float* __restrict__ tbl)
{
  __shared__ __align__(16) float sm[L_TOT];
  float* espan = sm + L_ESP;
  float* obsT  = sm + L_OBS;     // [k][r], stride 8
  float* hbuf  = sm + L_HBUF;    // [r][f], stride 260
  float* part  = sm + L_PART;    // [w][r][f]
  float* hcL   = sm + L_HCL;     // [r][c], stride 36
  float* cWs   = sm + L_CWS;     // [c][k], stride 260
  float* ts    = sm + L_PART;    // tail-weight stage (after GN1 frees part)

  const int tid = threadIdx.x;
  const int w   = tid >> 6;      // wave 0..3
  const int l   = tid & 63;      // lane
  const int rG  = tid >> 5;      // row-group 0..7 (GN + phase G)
  const int cG  = tid & 31;      // col within group
  const int s0  = blockIdx.x * R;

  // ---- Phase A: shared error span (edge-clamped == jnp.pad 'edge') ----
  for (int t = tid; t < WINDOW + R - 1; t += 256) {
    int c = s0 - HALF + t;
    c = c < 0 ? 0 : (c > NP - 1 ? NP - 1 : c);
    espan[t] = zc[c] - zt[c];
  }
  __syncthreads();

  // Issue cW-top staging loads (8 float4/thread) — complete during Phase B.
  float4 cwr[8];
#pragma unroll
  for (int j = 0; j < 8; ++j)
    cwr[j] = ((const float4*)cW)[tid + 256 * j];

  // prefetch layer-0 first weight row (completes during Phase B)
  const float* w0p = bW0 + (w * 10) * 256 + 4 * l;
  float4 wt0_n = *(const float4*)w0p;

  // ---- Phase B: bilinear-antialias resize of err & gradient -> obsT[40][8] ----
  {
    const float INV  = (float)WINDOW / (float)RL;   // 16.35
    const float RINV = (float)RL / (float)WINDOW;
    for (int task = tid; task < R * 2 * RL; task += 256) {   // 320 tasks
      int q = task % (2 * RL);
      int r = task / (2 * RL);
      int qq = (q < RL) ? q : q - RL;
      float xs = ((float)qq + 0.5f) * INV - 0.5f;
      int jlo = (int)ceilf(xs - INV);  if (jlo < 0) jlo = 0;
      int jhi = (int)floorf(xs + INV); if (jhi > WINDOW - 1) jhi = WINDOW - 1;
      const float* p = espan + r;
      float wsum = 0.0f, acc2 = 0.0f;
      for (int j = jlo; j <= jhi; ++j) {
        float wq = 1.0f - fabsf(xs - (float)j) * RINV;
        float v;
        if (q < RL) {
          v = p[j];
        } else {  // jnp.gradient on the window
          v = (j == 0) ? (p[1] - p[0]) :
              (j == WINDOW - 1) ? (p[WINDOW - 1] - p[WINDOW - 2]) :
              0.5f * (p[j + 1] - p[j - 1]);
        }
        wsum += wq;
        acc2 += wq * v;
      }
      obsT[q * 8 + r] = acc2 / wsum;
    }
  }

  // Write staged cW-top transposed: cWs[c][k], stride 260
#pragma unroll
  for (int j = 0; j < 8; ++j) {
    int idx = tid + 256 * j;
    int k  = idx >> 3;
    int c0 = (idx & 7) * 4;
    cWs[(c0    ) * 260 + k] = cwr[j].x;
    cWs[(c0 + 1) * 260 + k] = cwr[j].y;
    cWs[(c0 + 2) * 260 + k] = cwr[j].z;
    cWs[(c0 + 3) * 260 + k] = cwr[j].w;
  }
  __syncthreads();

  float acc[R][4];

  // ---- Layer 0 (40 -> 256), k-split 4-way, 1-deep weight prefetch ----
#pragma unroll
  for (int r = 0; r < R; ++r) { acc[r][0]=0.f; acc[r][1]=0.f; acc[r][2]=0.f; acc[r][3]=0.f; }
#pragma unroll
  for (int kk = 0; kk < 10; ++kk) {
    float4 wt = wt0_n;
    if (kk < 9) wt0_n = *(const float4*)(w0p + (kk + 1) * 256);
    int k = w * 10 + kk;
    float4 o0 = *(const float4*)&obsT[k * 8];
    float4 o1 = *(const float4*)&obsT[k * 8 + 4];
    const float os[8] = {o0.x, o0.y, o0.z, o0.w, o1.x, o1.y, o1.z, o1.w};
    const float wv[4] = {wt.x, wt.y, wt.z, wt.w};
#pragma unroll
    for (int r = 0; r < R; ++r)
#pragma unroll
      for (int j = 0; j < 4; ++j) acc[r][j] = fmaf(os[r], wv[j], acc[r][j]);
  }
#pragma unroll
  for (int r = 0; r < R; ++r)
    *(float4*)&part[w * 2048 + r * 256 + 4 * l] = make_float4(acc[r][0], acc[r][1], acc[r][2], acc[r][3]);
  __syncthreads();

  // ---- GN0 + tanh (and prefetch layer-1 first 4 weight rows during it) ----
  const float* w1p = bW1 + (w * 64) * 256 + 4 * l;
  float4 wt_n0 = *(const float4*)(w1p);
  float4 wt_n1 = *(const float4*)(w1p + 256);
  float4 wt_n2 = *(const float4*)(w1p + 512);
  float4 wt_n3 = *(const float4*)(w1p + 768);
  {
    float val[8];
    {
      float4 b0 = *(const float4*)&bb0[8 * cG];
      float4 b1 = *(const float4*)&bb0[8 * cG + 4];
      val[0]=b0.x; val[1]=b0.y; val[2]=b0.z; val[3]=b0.w;
      val[4]=b1.x; val[5]=b1.y; val[6]=b1.z; val[7]=b1.w;
    }
#pragma unroll
    for (int w2 = 0; w2 < 4; ++w2) {
      float4 p0 = *(const float4*)&part[w2 * 2048 + rG * 256 + 8 * cG];
      float4 p1 = *(const float4*)&part[w2 * 2048 + rG * 256 + 8 * cG + 4];
      val[0]+=p0.x; val[1]+=p0.y; val[2]+=p0.z; val[3]+=p0.w;
      val[4]+=p1.x; val[5]+=p1.y; val[6]+=p1.z; val[7]+=p1.w;
    }
    float s = 0.f, q = 0.f;
#pragma unroll
    for (int i = 0; i < 8; ++i) { s += val[i]; q += val[i] * val[i]; }
    halfwave_sum2(s, q);
    float mu  = s * (1.0f / 256.0f);
    float var = fmaxf(q * (1.0f / 256.0f) - mu * mu, 0.0f);
    float rv  = rsqrtf(var + GN_EPS);
    float4 sc0 = *(const float4*)&bs0[8 * cG];
    float4 sc1 = *(const float4*)&bs0[8 * cG + 4];
    float4 sh0 = *(const float4*)&bB0[8 * cG];
    float4 sh1 = *(const float4*)&bB0[8 * cG + 4];
    const float sc[8] = {sc0.x,sc0.y,sc0.z,sc0.w,sc1.x,sc1.y,sc1.z,sc1.w};
    const float sh[8] = {sh0.x,sh0.y,sh0.z,sh0.w,sh1.x,sh1.y,sh1.z,sh1.w};
    float h[8];
#pragma unroll
    for (int i = 0; i < 8; ++i) h[i] = tanh_fast((val[i] - mu) * rv * sc[i] + sh[i]);
    *(float4*)&hbuf[rG * 260 + 8 * cG]     = make_float4(h[0], h[1], h[2], h[3]);
    *(float4*)&hbuf[rG * 260 + 8 * cG + 4] = make_float4(h[4], h[5], h[6], h[7]);
  }
  __syncthreads();

  // ---- Layer 1 (256 -> 256), k-split 4-way, 4-row weight prefetch ----
#pragma unroll
  for (int r = 0; r < R; ++r) { acc[r][0]=0.f; acc[r][1]=0.f; acc[r][2]=0.f; acc[r][3]=0.f; }
  for (int kk = 0; kk < 64; kk += 4) {
    float4 wt0 = wt_n0, wt1 = wt_n1, wt2 = wt_n2, wt3 = wt_n3;
    if (kk < 60) {
      wt_n0 = *(const float4*)(w1p + (kk + 4) * 256);
      wt_n1 = *(const float4*)(w1p + (kk + 5) * 256);
      wt_n2 = *(const float4*)(w1p + (kk + 6) * 256);
      wt_n3 = *(const float4*)(w1p + (kk + 7) * 256);
    }
    int k0 = w * 64 + kk;
#pragma unroll
    for (int r = 0; r < R; ++r) {
      float4 hv = *(const float4*)&hbuf[r * 260 + k0];   // broadcast
      acc[r][0] = fmaf(hv.x, wt0.x, acc[r][0]); acc[r][1] = fmaf(hv.x, wt0.y, acc[r][1]);
      acc[r][2] = fmaf(hv.x, wt0.z, acc[r][2]); acc[r][3] = fmaf(hv.x, wt0.w, acc[r][3]);
      acc[r][0] = fmaf(hv.y, wt1.x, acc[r][0]); acc[r][1] = fmaf(hv.y, wt1.y, acc[r][1]);
      acc[r][2] = fmaf(hv.y, wt1.z, acc[r][2]); acc[r][3] = fmaf(hv.y, wt1.w, acc[r][3]);
      acc[r][0] = fmaf(hv.z, wt2.x, acc[r][0]); acc[r][1] = fmaf(hv.z, wt2.y, acc[r][1]);
      acc[r][2] = fmaf(hv.z, wt2.z, acc[r][2]); acc[r][3] = fmaf(hv.z, wt2.w, acc[r][3]);
      acc[r][0] = fmaf(hv.w, wt3.x, acc[r][0]); acc[r][1] = fmaf(hv.w, wt3.y, acc[r][1]);
      acc[r][2] = fmaf(hv.w, wt3.z, acc[r][2]); acc[r][3] = fmaf(hv.w, wt3.w, acc[r][3]);
    }
  }
#pragma unroll
  for (int r = 0; r < R; ++r)
    *(float4*)&part[w * 2048 + r * 256 + 4 * l] = make_float4(acc[r][0], acc[r][1], acc[r][2], acc[r][3]);
  __syncthreads();   // orders all hbuf(h0) reads before GN1's hbuf writes

  // ---- GN1 + tanh (prefetch cb during it) ----
  float cbv = cb[cG];
  {
    float val[8];
    {
      float4 b0 = *(const float4*)&bb1[8 * cG];
      float4 b1 = *(const float4*)&bb1[8 * cG + 4];
      val[0]=b0.x; val[1]=b0.y; val[2]=b0.z; val[3]=b0.w;
      val[4]=b1.x; val[5]=b1.y; val[6]=b1.z; val[7]=b1.w;
    }
#pragma unroll
    for (int w2 = 0; w2 < 4; ++w2) {
      float4 p0 = *(const float4*)&part[w2 * 2048 + rG * 256 + 8 * cG];
      float4 p1 = *(const float4*)&part[w2 * 2048 + rG * 256 + 8 * cG + 4];
      val[0]+=p0.x; val[1]+=p0.y; val[2]+=p0.z; val[3]+=p0.w;
      val[4]+=p1.x; val[5]+=p1.y; val[6]+=p1.z; val[7]+=p1.w;
    }
    float s = 0.f, q = 0.f;
#pragma unroll
    for (int i = 0; i < 8; ++i) { s += val[i]; q += val[i] * val[i]; }
    halfwave_sum2(s, q);
    float mu  = s * (1.0f / 256.0f);
    float var = fmaxf(q * (1.0f / 256.0f) - mu * mu, 0.0f);
    float rv  = rsqrtf(var + GN_EPS);
    float4 sc0 = *(const float4*)&bs1[8 * cG];
    float4 sc1 = *(const float4*)&bs1[8 * cG + 4];
    float4 sh0 = *(const float4*)&bB1[8 * cG];
    float4 sh1 = *(const float4*)&bB1[8 * cG + 4];
    const float sc[8] = {sc0.x,sc0.y,sc0.z,sc0.w,sc1.x,sc1.y,sc1.z,sc1.w};
    const float sh[8] = {sh0.x,sh0.y,sh0.z,sh0.w,sh1.x,sh1.y,sh1.z,sh1.w};
    float h[8];
#pragma unroll
    for (int i = 0; i < 8; ++i) h[i] = tanh_fast((val[i] - mu) * rv * sc[i] + sh[i]);
    *(float4*)&hbuf[rG * 260 + 8 * cG]     = make_float4(h[0], h[1], h[2], h[3]);
    *(float4*)&hbuf[rG * 260 + 8 * cG + 4] = make_float4(h[4], h[5], h[6], h[7]);
  }
  __syncthreads();   // GN1 part-reads done; part area now reusable for tail stage

  // Issue tail-weight staging loads (consumed after the next barrier; the G
  // loop below hides their latency).
  float4 stA = make_float4(0,0,0,0), stB, stC, stD = make_float4(0,0,0,0);
  float stUB = 0.f, stVB = 0.f;
  if (tid < 64) stA = ((const float4*)tW0)[tid];
  stB = ((const float4*)tW1)[tid];
  stC = ((const float4*)(cW + 256 * 32))[tid];
  if (tid < 32) {
    const float* srcs[4] = {tb0, tb1, uW, vW};
    stD = ((const float4*)srcs[tid >> 3])[tid & 7];
  }
  if (tid == 32) stUB = ub[0];
  if (tid == 33) stVB = vb[0];

  // ---- Phase G: hcL[r][c] = cb[c] + h1[r,:].cW_top[:,c] (cW from LDS) ----
  {
    float ga = 0.0f;
#pragma unroll 4
    for (int k = 0; k < 256; k += 8) {
      float4 h0 = *(const float4*)&hbuf[rG * 260 + k];
      float4 h1 = *(const float4*)&hbuf[rG * 260 + k + 4];
      float4 w0 = *(const float4*)&cWs[cG * 260 + k];
      float4 w1 = *(const float4*)&cWs[cG * 260 + k + 4];
      ga = fmaf(h0.x, w0.x, ga); ga = fmaf(h0.y, w0.y, ga);
      ga = fmaf(h0.z, w0.z, ga); ga = fmaf(h0.w, w0.w, ga);
      ga = fmaf(h1.x, w1.x, ga); ga = fmaf(h1.y, w1.y, ga);
      ga = fmaf(h1.z, w1.z, ga); ga = fmaf(h1.w, w1.w, ga);
    }
    hcL[rG * 36 + cG] = ga + cbv;
  }

  // write staged tail weights to LDS (part area)
  if (tid < 64) ((float4*)(ts + TS_TW0))[tid] = stA;
  ((float4*)(ts + TS_TW1))[tid & 255] = stB;   // 256 float4s
  ((float4*)(ts + TS_CWB))[tid & 255] = stC;
  if (tid < 8)  ((float4*)(ts + TS_TB0))[tid] = stD;
  else if (tid < 16) ((float4*)(ts + TS_TB1))[tid - 8]  = stD;
  else if (tid < 24) ((float4*)(ts + TS_UW))[tid - 16] = stD;
  else if (tid < 32) ((float4*)(ts + TS_VW))[tid - 24] = stD;
  if (tid == 32) ts[TS_UB] = stUB;
  if (tid == 33) ts[TS_VB] = stVB;
  __syncthreads();

  // ---- Tail: 16 endpoint evals (8 bins x {left,right}), 8 threads each ----
  if (tid < 128) {
    int v = tid >> 3, sub = tid & 7;
    int r = v >> 1, e = v & 1;
    int jg = s0 + r + e;
    float xe = (float)jg * (1.0f / 4095.0f);
    float enc[8];
#pragma unroll
    for (int k = 0; k < 4; ++k) {
      float fr = (float)(1 << k);
      float a = (xe * fr) * 3.14159265358979f;
      enc[k]     = sinf(a);
      enc[k + 4] = cosf(a);
    }
    int base = (tid & 63) & ~7;

    float t0v[4];
    {
      float4 b = *(const float4*)&ts[TS_TB0 + 4 * sub];
      t0v[0]=b.x; t0v[1]=b.y; t0v[2]=b.z; t0v[3]=b.w;
    }
#pragma unroll
    for (int k = 0; k < 8; ++k) {
      float4 wq = *(const float4*)&ts[TS_TW0 + k * 32 + 4 * sub];
      t0v[0] = fmaf(enc[k], wq.x, t0v[0]);
      t0v[1] = fmaf(enc[k], wq.y, t0v[1]);
      t0v[2] = fmaf(enc[k], wq.z, t0v[2]);
      t0v[3] = fmaf(enc[k], wq.w, t0v[3]);
    }
#pragma unroll
    for (int i = 0; i < 4; ++i) t0v[i] = tanh_fast(t0v[i]);

    float t1v[4];
    {
      float4 b = *(const float4*)&ts[TS_TB1 + 4 * sub];
      t1v[0]=b.x; t1v[1]=b.y; t1v[2]=b.z; t1v[3]=b.w;
    }
#pragma unroll
    for (int j8 = 0; j8 < 8; ++j8) {
#pragma unroll
      for (int i2 = 0; i2 < 4; ++i2) {
        float tv = __shfl(t0v[i2], base + j8, 64);
        float4 wq = *(const float4*)&ts[TS_TW1 + (4 * j8 + i2) * 32 + 4 * sub];
        t1v[0] = fmaf(tv, wq.x, t1v[0]);
        t1v[1] = fmaf(tv, wq.y, t1v[1]);
        t1v[2] = fmaf(tv, wq.z, t1v[2]);
        t1v[3] = fmaf(tv, wq.w, t1v[3]);
      }
    }
#pragma unroll
    for (int i = 0; i < 4; ++i) t1v[i] = tanh_fast(t1v[i]);

    float xvv[4];
    {
      float4 hq = *(const float4*)&hcL[r * 36 + 4 * sub];
      xvv[0]=hq.x; xvv[1]=hq.y; xvv[2]=hq.z; xvv[3]=hq.w;
    }
#pragma unroll
    for (int j8 = 0; j8 < 8; ++j8) {
#pragma unroll
      for (int i2 = 0; i2 < 4; ++i2) {
        float tv = __shfl(t1v[i2], base + j8, 64);
        float4 wq = *(const float4*)&ts[TS_CWB + (4 * j8 + i2) * 32 + 4 * sub];
        xvv[0] = fmaf(tv, wq.x, xvv[0]);
        xvv[1] = fmaf(tv, wq.y, xvv[1]);
        xvv[2] = fmaf(tv, wq.z, xvv[2]);
        xvv[3] = fmaf(tv, wq.w, xvv[3]);
      }
    }
#pragma unroll
    for (int i = 0; i < 4; ++i) xvv[i] = tanh_fast(xvv[i]);

    float4 wu = *(const float4*)&ts[TS_UW + 4 * sub];
    float4 wv = *(const float4*)&ts[TS_VW + 4 * sub];
    float up = xvv[0]*wu.x + xvv[1]*wu.y + xvv[2]*wu.z + xvv[3]*wu.w;
    float vp = xvv[0]*wv.x + xvv[1]*wv.y + xvv[2]*wv.z + xvv[3]*wv.w;
#pragma unroll
    for (int m = 1; m < 8; m <<= 1) {
      up += __shfl_xor(up, m, 64);
      vp += __shfl_xor(vp, m, 64);
    }
    if (sub == 0) {
      int s = s0 + r;
      tbl[4 * s + e]     = 40.0f * tanh_fast(up + ts[TS_UB]);
      tbl[4 * s + 2 + e] = tanh_fast(vp + ts[TS_VB]);
    }
  }
}

// ---------------- Kernel 2: agents = bin + lerp ----------------
__global__ __launch_bounds__(256) void dc_agents(
    const float* __restrict__ xi_curr, const float4* __restrict__ tbl,
    float* __restrict__ out)
{
  int a = blockIdx.x * 256 + threadIdx.x;
  float xi = xi_curr[a];
  float p = xi * 4095.0f;           // same fp32 product the reference truncates
  int s = (int)p;
  s = s > 4095 ? 4095 : s;
  float t = p - (float)s;           // exact (Sterbenz)
  float4 tb = tbl[s];               // {u_l, u_r, v_l, v_r}
  out[a]      = fmaf(t, tb.y - tb.x, tb.x);
  out[NA + a] = fmaf(t, tb.w - tb.z, tb.z);
}

extern "C" void kernel_launch(void* const* d_in, const int* in_sizes, int n_in,
                              void* d_out, int out_size, void* d_ws, size_t ws_size,
                              hipStream_t stream) {
  const float* zc  = (const float*)d_in[0];
  const float* zt  = (const float*)d_in[1];
  const float* xi  = (const float*)d_in[2];
  const float* bW0 = (const float*)d_in[3];
  const float* bb0 = (const float*)d_in[4];
  const float* bs0 = (const float*)d_in[5];
  const float* bB0 = (const float*)d_in[6];
  const float* bW1 = (const float*)d_in[7];
  const float* bb1 = (const float*)d_in[8];
  const float* bs1 = (const float*)d_in[9];
  const float* bB1 = (const float*)d_in[10];
  const float* tW0 = (const float*)d_in[11];
  const float* tb0 = (const float*)d_in[12];
  const float* tW1 = (const float*)d_in[13];
  const float* tb1 = (const float*)d_in[14];
  const float* cW  = (const float*)d_in[15];
  const float* cb  = (const float*)d_in[16];
  const float* uW  = (const float*)d_in[17];
  const float* ub  = (const float*)d_in[18];
  const float* vW  = (const float*)d_in[19];
  const float* vb  = (const float*)d_in[20];

  float* tbl = (float*)d_ws;        // 4096 x float4 = 64 KB
  float* out = (float*)d_out;

  dc_table<<<NBLK, 256, 0, stream>>>(zc, zt, bW0, bb0, bs0, bB0,
                                     bW1, bb1, bs1, bB1,
                                     tW0, tb0, tW1, tb1, cW, cb,
                                     uW, ub, vW, vb, tbl);
  dc_agents<<<NA / 256, 256, 0, stream>>>(xi, (const float4*)tbl, out);
}